// Round 1
// baseline (200.005 us; speedup 1.0000x reference)
//
#include <hip/hip_runtime.h>
#include <hip/hip_bf16.h>

#define N_NODES 50000
#define E_EDGES 800000
#define IN_DIM  256
#define HID     128
#define OUT_DIM 16

#define NBUCK 391    // ceil(50000/128) buckets of 128 nodes (dst>>7)
#define NBLK  128    // blocks for bucket phases A/C
#define P2CAP 4096   // max edges per bucket (mean 2046, sigma ~45)
#define GB1   391    // gemm1 blocks: ceil(50000/128)

using frag_ab = __attribute__((ext_vector_type(8))) short;  // 8 bf16
using frag_cd = __attribute__((ext_vector_type(4))) float;  // 4 fp32

static __device__ inline short f2bf(float f) {
    union { float f; unsigned u; } v; v.f = f;
    unsigned r = (v.u + 0x7fffu + ((v.u >> 16) & 1u)) >> 16;
    return (short)r;
}
static __device__ inline float bflo(unsigned u) {
    union { unsigned u; float f; } v; v.u = u << 16; return v.f;
}
static __device__ inline float bfhi(unsigned u) {
    union { unsigned u; float f; } v; v.u = u & 0xffff0000u; return v.f;
}
static __device__ inline unsigned packbf(float a, float b) {
    return (unsigned)(unsigned short)f2bf(a) | ((unsigned)(unsigned short)f2bf(b) << 16);
}

// ========== K1: gemm1 (inline W1 transform, UNSCALED h1s)  ||  csr_a =========
// blocks [0, GB1): layer-1 dense transform, h1s = bf16(x @ W1)  (no dinv)
// blocks [GB1, GB1+NBLK): dst histogram into per-block bucket counts
__global__ __launch_bounds__(512) void k1_gemm1_csra(const float* __restrict__ x,
                                                     const float* __restrict__ W1,
                                                     const int4* __restrict__ dst4,
                                                     int* __restrict__ cnt_bb,
                                                     short* __restrict__ h1s) {
    __shared__ uint4 lwt[64 * 64];   // 64 KB (aliased as int hist[] for csr_a blocks)
    int tid = threadIdx.x;

    if (blockIdx.x >= GB1) {
        // ---- csr_a: bucket histogram (512-thread partition; csr_c must match!)
        int* hist = (int*)lwt;
        int bb = blockIdx.x - GB1;
        for (int i = tid; i < NBUCK; i += 512) hist[i] = 0;
        __syncthreads();
        for (int i = bb * 512 + tid; i < E_EDGES / 4; i += NBLK * 512) {
            int4 d = dst4[i];
            atomicAdd(&hist[d.x >> 7], 1);
            atomicAdd(&hist[d.y >> 7], 1);
            atomicAdd(&hist[d.z >> 7], 1);
            atomicAdd(&hist[d.w >> 7], 1);
        }
        __syncthreads();
        for (int i = tid; i < NBUCK; i += 512) cnt_bb[i * NBLK + bb] = hist[i];
        return;
    }

    // ---- gemm1: build fragment-major bf16 W1 tile in LDS directly from f32 W1
#pragma unroll
    for (int it = 0; it < 8; ++it) {
        int j = it * 512 + tid;
        int f = j >> 6, lane_ = j & 63;
        int kt = f >> 3, tt = f & 7;
        int mm = lane_ & 15, qq = lane_ >> 4;
        int c = tt * 16 + mm;
        int k0 = kt * 32 + qq * 8;
        unsigned p[4];
#pragma unroll
        for (int i = 0; i < 4; ++i)
            p[i] = packbf(W1[(k0 + 2 * i) * HID + c], W1[(k0 + 2 * i + 1) * HID + c]);
        uint4 v; v.x = p[0]; v.y = p[1]; v.z = p[2]; v.w = p[3];
        lwt[j] = v;
    }

    int wave = tid >> 6;
    int lane = tid & 63;
    int m = lane & 15;
    int q = lane >> 4;
    int row0 = blockIdx.x * 128 + wave * 16;
    int arow_idx = row0 + m;
    const float4* arow4 = (const float4*)(x + (size_t)(arow_idx < N_NODES ? arow_idx : 0) * IN_DIM);

    frag_ab a[8];
#pragma unroll
    for (int kt = 0; kt < 8; ++kt) {
        float4 f0 = arow4[kt * 8 + q * 2];
        float4 f1 = arow4[kt * 8 + q * 2 + 1];
        a[kt][0] = f2bf(f0.x); a[kt][1] = f2bf(f0.y); a[kt][2] = f2bf(f0.z); a[kt][3] = f2bf(f0.w);
        a[kt][4] = f2bf(f1.x); a[kt][5] = f2bf(f1.y); a[kt][6] = f2bf(f1.z); a[kt][7] = f2bf(f1.w);
    }

    frag_cd acc[8];
#pragma unroll
    for (int t = 0; t < 8; ++t) acc[t] = frag_cd{0.f, 0.f, 0.f, 0.f};

    __syncthreads();

#pragma unroll
    for (int kt = 0; kt < 8; ++kt) {
#pragma unroll
        for (int t = 0; t < 8; ++t) {
            frag_ab b = *(const frag_ab*)&lwt[(kt * 8 + t) * 64 + lane];
            acc[t] = __builtin_amdgcn_mfma_f32_16x16x32_bf16(a[kt], b, acc[t], 0, 0, 0);
        }
    }

#pragma unroll
    for (int t = 0; t < 8; ++t) {
#pragma unroll
        for (int r = 0; r < 4; ++r) {
            int orow = row0 + q * 4 + r;
            if (orow < N_NODES)
                h1s[(size_t)orow * HID + t * 16 + m] = f2bf(acc[t][r]);   // unscaled
        }
    }
}

// ========== K2: per-bucket exclusive scan over blocks (unchanged) ===========
__global__ __launch_bounds__(NBLK) void csr_b1(int* __restrict__ cnt_bb,
                                               int* __restrict__ btot) {
    __shared__ int sm[NBLK];
    int b = blockIdx.x, t = threadIdx.x;
    int v = cnt_bb[b * NBLK + t];
    sm[t] = v;
    __syncthreads();
    for (int o = 1; o < NBLK; o <<= 1) {
        int u = (t >= o) ? sm[t - o] : 0;
        __syncthreads();
        sm[t] += u;
        __syncthreads();
    }
    cnt_bb[b * NBLK + t] = sm[t] - v;
    if (t == NBLK - 1) btot[b] = sm[t];
}

// ========== K3: csr_c with inline bucket-base scan (drops csr_b2) ===========
// every block recomputes the 391-wide exclusive scan of btot in LDS (~1 us);
// block 0 publishes bbase for csr_p2.
__global__ __launch_bounds__(512) void csr_c2(const int4* __restrict__ src4,
                                              const int4* __restrict__ dst4,
                                              const int* __restrict__ cnt_bb,
                                              const int* __restrict__ btot,
                                              int* __restrict__ bbase,
                                              unsigned* __restrict__ tmp) {
    __shared__ int run[NBUCK];
    __shared__ int sc[512];
    int t = threadIdx.x;
    int v = (t < NBUCK) ? btot[t] : 0;
    sc[t] = v;
    __syncthreads();
    for (int o = 1; o < 512; o <<= 1) {
        int u = (t >= o) ? sc[t - o] : 0;
        __syncthreads();
        sc[t] += u;
        __syncthreads();
    }
    if (t < NBUCK) {
        int exc = sc[t] - v;
        run[t] = exc + cnt_bb[t * NBLK + blockIdx.x];
        if (blockIdx.x == 0) bbase[t] = exc;
    }
    if (blockIdx.x == 0 && t == 511) bbase[NBUCK] = sc[511];
    __syncthreads();
    for (int i = blockIdx.x * 512 + t; i < E_EDGES / 4; i += NBLK * 512) {
        int4 d = dst4[i];
        int4 s = src4[i];
        int p0 = atomicAdd(&run[d.x >> 7], 1);
        tmp[p0] = (unsigned)s.x | ((unsigned)(d.x & 127) << 17);
        int p1 = atomicAdd(&run[d.y >> 7], 1);
        tmp[p1] = (unsigned)s.y | ((unsigned)(d.y & 127) << 17);
        int p2 = atomicAdd(&run[d.z >> 7], 1);
        tmp[p2] = (unsigned)s.z | ((unsigned)(d.z & 127) << 17);
        int p3 = atomicAdd(&run[d.w >> 7], 1);
        tmp[p3] = (unsigned)s.w | ((unsigned)(d.w & 127) << 17);
    }
}

// ========== K4: within-bucket counting sort -> rowptr/dinv/ssrc (unchanged) =
__global__ __launch_bounds__(256) void csr_p2(const unsigned* __restrict__ tmp,
                                              const int* __restrict__ bbase,
                                              int* __restrict__ rowptr,
                                              float* __restrict__ dinv,
                                              int* __restrict__ ssrc) {
    __shared__ unsigned ed[P2CAP];
    __shared__ int cnt[128];
    __shared__ int off[128];
    int b = blockIdx.x, t = threadIdx.x;
    int base = bbase[b];
    int m = bbase[b + 1] - base;
    if (m > P2CAP) m = P2CAP;
    if (t < 128) cnt[t] = 0;
    __syncthreads();
    for (int i = t; i < m; i += 256) {
        unsigned v = tmp[base + i];
        ed[i] = v;
        atomicAdd(&cnt[v >> 17], 1);
    }
    __syncthreads();
    if (t < 128) off[t] = cnt[t];
    __syncthreads();
    for (int o = 1; o < 128; o <<= 1) {
        int u = (t >= o && t < 128) ? off[t - o] : 0;
        __syncthreads();
        if (t < 128) off[t] += u;
        __syncthreads();
    }
    if (t < 128) {
        int node = b * 128 + t;
        int ex = off[t] - cnt[t];
        if (node < N_NODES) {
            rowptr[node] = base + ex;
            dinv[node] = rsqrtf((float)(cnt[t] + 1));
        }
        off[t] = ex;
    }
    if (b == NBUCK - 1 && t == 0) rowptr[N_NODES] = E_EDGES;
    __syncthreads();
    for (int i = t; i < m; i += 256) {
        unsigned v = ed[i];
        int p = atomicAdd(&off[v >> 17], 1);
        ssrc[base + p] = (int)(v & 0x1FFFF);
    }
}

// ========== K5: fused agg1 (per-edge dinv[s] fma) + relu + W2 + dinv[d] =====
// grid-strided; W2 (128x16 f32) cached in 32 regs/lane, loaded once per block.
__global__ __launch_bounds__(256) void agg1_gemm2(const short* __restrict__ h1s,
                                                  const float* __restrict__ dinv,
                                                  const float* __restrict__ b1,
                                                  const float* __restrict__ W2,
                                                  const int* __restrict__ rowptr,
                                                  const int* __restrict__ ssrc,
                                                  short* __restrict__ h2s) {
    int wave = threadIdx.x >> 6;
    int lane = threadIdx.x & 63;
    int eo = lane >> 4;       // edge slot in quad / output col group
    int g  = lane & 15;       // feature octet

    float4 w2r[8];
#pragma unroll
    for (int i = 0; i < 8; ++i)
        w2r[i] = *(const float4*)(W2 + (g * 8 + i) * OUT_DIM + eo * 4);
    float4 bA = *(const float4*)(b1 + g * 8);
    float4 bB = *(const float4*)(b1 + g * 8 + 4);

    for (int node = __builtin_amdgcn_readfirstlane(blockIdx.x * 4 + wave);
         node < N_NODES; node += gridDim.x * 4) {
        int lo = rowptr[node], hi = rowptr[node + 1];
        float dd = dinv[node];
        float a0 = 0.f, a1 = 0.f, a2 = 0.f, a3 = 0.f;
        float a4 = 0.f, a5 = 0.f, a6 = 0.f, a7 = 0.f;

        if (eo == 0) {   // self-loop: h[d] * dinv[d]
            uint4 u = *(const uint4*)(h1s + (size_t)node * HID + g * 8);
            a0 = dd * bflo(u.x); a1 = dd * bfhi(u.x);
            a2 = dd * bflo(u.y); a3 = dd * bfhi(u.y);
            a4 = dd * bflo(u.z); a5 = dd * bfhi(u.z);
            a6 = dd * bflo(u.w); a7 = dd * bfhi(u.w);
        }

        int e = lo;
        for (; e + 16 <= hi; e += 16) {
            int s0 = ssrc[e + eo];
            int s1 = ssrc[e + 4 + eo];
            int s2 = ssrc[e + 8 + eo];
            int s3 = ssrc[e + 12 + eo];
            float d0 = dinv[s0], d1 = dinv[s1], d2 = dinv[s2], d3 = dinv[s3];
            uint4 u0 = *(const uint4*)(h1s + (size_t)s0 * HID + g * 8);
            uint4 u1 = *(const uint4*)(h1s + (size_t)s1 * HID + g * 8);
            uint4 u2 = *(const uint4*)(h1s + (size_t)s2 * HID + g * 8);
            uint4 u3 = *(const uint4*)(h1s + (size_t)s3 * HID + g * 8);
            a0 = fmaf(d0, bflo(u0.x), a0); a1 = fmaf(d0, bfhi(u0.x), a1);
            a2 = fmaf(d0, bflo(u0.y), a2); a3 = fmaf(d0, bfhi(u0.y), a3);
            a4 = fmaf(d0, bflo(u0.z), a4); a5 = fmaf(d0, bfhi(u0.z), a5);
            a6 = fmaf(d0, bflo(u0.w), a6); a7 = fmaf(d0, bfhi(u0.w), a7);
            a0 = fmaf(d1, bflo(u1.x), a0); a1 = fmaf(d1, bfhi(u1.x), a1);
            a2 = fmaf(d1, bflo(u1.y), a2); a3 = fmaf(d1, bfhi(u1.y), a3);
            a4 = fmaf(d1, bflo(u1.z), a4); a5 = fmaf(d1, bfhi(u1.z), a5);
            a6 = fmaf(d1, bflo(u1.w), a6); a7 = fmaf(d1, bfhi(u1.w), a7);
            a0 = fmaf(d2, bflo(u2.x), a0); a1 = fmaf(d2, bfhi(u2.x), a1);
            a2 = fmaf(d2, bflo(u2.y), a2); a3 = fmaf(d2, bfhi(u2.y), a3);
            a4 = fmaf(d2, bflo(u2.z), a4); a5 = fmaf(d2, bfhi(u2.z), a5);
            a6 = fmaf(d2, bflo(u2.w), a6); a7 = fmaf(d2, bfhi(u2.w), a7);
            a0 = fmaf(d3, bflo(u3.x), a0); a1 = fmaf(d3, bfhi(u3.x), a1);
            a2 = fmaf(d3, bflo(u3.y), a2); a3 = fmaf(d3, bfhi(u3.y), a3);
            a4 = fmaf(d3, bflo(u3.z), a4); a5 = fmaf(d3, bfhi(u3.z), a5);
            a6 = fmaf(d3, bflo(u3.w), a6); a7 = fmaf(d3, bfhi(u3.w), a7);
        }
        for (; e + 4 <= hi; e += 4) {
            int s = ssrc[e + eo];
            float ds_ = dinv[s];
            uint4 u = *(const uint4*)(h1s + (size_t)s * HID + g * 8);
            a0 = fmaf(ds_, bflo(u.x), a0); a1 = fmaf(ds_, bfhi(u.x), a1);
            a2 = fmaf(ds_, bflo(u.y), a2); a3 = fmaf(ds_, bfhi(u.y), a3);
            a4 = fmaf(ds_, bflo(u.z), a4); a5 = fmaf(ds_, bfhi(u.z), a5);
            a6 = fmaf(ds_, bflo(u.w), a6); a7 = fmaf(ds_, bfhi(u.w), a7);
        }
        if (eo < hi - e) {
            int s = ssrc[e + eo];
            float ds_ = dinv[s];
            uint4 u = *(const uint4*)(h1s + (size_t)s * HID + g * 8);
            a0 = fmaf(ds_, bflo(u.x), a0); a1 = fmaf(ds_, bfhi(u.x), a1);
            a2 = fmaf(ds_, bflo(u.y), a2); a3 = fmaf(ds_, bfhi(u.y), a3);
            a4 = fmaf(ds_, bflo(u.z), a4); a5 = fmaf(ds_, bfhi(u.z), a5);
            a6 = fmaf(ds_, bflo(u.w), a6); a7 = fmaf(ds_, bfhi(u.w), a7);
        }

        // reduce across the 4 edge slots (eo): every lane ends with full row
        a0 += __shfl_xor(a0, 16); a1 += __shfl_xor(a1, 16);
        a2 += __shfl_xor(a2, 16); a3 += __shfl_xor(a3, 16);
        a4 += __shfl_xor(a4, 16); a5 += __shfl_xor(a5, 16);
        a6 += __shfl_xor(a6, 16); a7 += __shfl_xor(a7, 16);
        a0 += __shfl_xor(a0, 32); a1 += __shfl_xor(a1, 32);
        a2 += __shfl_xor(a2, 32); a3 += __shfl_xor(a3, 32);
        a4 += __shfl_xor(a4, 32); a5 += __shfl_xor(a5, 32);
        a6 += __shfl_xor(a6, 32); a7 += __shfl_xor(a7, 32);

        // relu(dd * agg + b1)   (layer-1 output, f32)
        float vv[8];
        vv[0] = fmaxf(fmaf(dd, a0, bA.x), 0.f);
        vv[1] = fmaxf(fmaf(dd, a1, bA.y), 0.f);
        vv[2] = fmaxf(fmaf(dd, a2, bA.z), 0.f);
        vv[3] = fmaxf(fmaf(dd, a3, bA.w), 0.f);
        vv[4] = fmaxf(fmaf(dd, a4, bB.x), 0.f);
        vv[5] = fmaxf(fmaf(dd, a5, bB.y), 0.f);
        vv[6] = fmaxf(fmaf(dd, a6, bB.z), 0.f);
        vv[7] = fmaxf(fmaf(dd, a7, bB.w), 0.f);

        // layer-2 transform: lane (g,eo) covers k=8g..8g+7, j=4eo..4eo+3
        float p0 = 0.f, p1 = 0.f, p2 = 0.f, p3 = 0.f;
#pragma unroll
        for (int i = 0; i < 8; ++i) {
            p0 = fmaf(vv[i], w2r[i].x, p0);
            p1 = fmaf(vv[i], w2r[i].y, p1);
            p2 = fmaf(vv[i], w2r[i].z, p2);
            p3 = fmaf(vv[i], w2r[i].w, p3);
        }
        // reduce over k-octets (g = lane bits 0..3)
#pragma unroll
        for (int msk = 1; msk <= 8; msk <<= 1) {
            p0 += __shfl_xor(p0, msk); p1 += __shfl_xor(p1, msk);
            p2 += __shfl_xor(p2, msk); p3 += __shfl_xor(p3, msk);
        }
        if (g == 0) {
            uint2 st;
            st.x = packbf(p0 * dd, p1 * dd);
            st.y = packbf(p2 * dd, p3 * dd);
            *(uint2*)(h2s + (size_t)node * OUT_DIM + eo * 4) = st;
        }
    }
}

// ========== K6: layer-2 pull + bias + log_softmax (unchanged) ===============
__global__ __launch_bounds__(256) void agg2_pull(const unsigned* __restrict__ h2s,
                                                 const float* __restrict__ dinv,
                                                 const float* __restrict__ b2,
                                                 const int* __restrict__ rowptr,
                                                 const int* __restrict__ ssrc,
                                                 float* __restrict__ out) {
    int wave = threadIdx.x >> 6;
    int lane = threadIdx.x & 63;
    int node = __builtin_amdgcn_readfirstlane(blockIdx.x * 4 + wave);
    if (node >= N_NODES) return;
    int eo = lane >> 3;
    int g  = lane & 7;

    int lo = rowptr[node], hi = rowptr[node + 1];
    float a0 = 0.f, a1 = 0.f;
    if (eo == 0) {
        unsigned u = h2s[(size_t)node * 8 + g];
        a0 = bflo(u); a1 = bfhi(u);
    }
    int e = lo;
    for (; e + 16 <= hi; e += 16) {
        int s0 = ssrc[e + eo];
        int s1 = ssrc[e + 8 + eo];
        unsigned u0 = h2s[(size_t)s0 * 8 + g];
        unsigned u1 = h2s[(size_t)s1 * 8 + g];
        a0 += bflo(u0); a1 += bfhi(u0);
        a0 += bflo(u1); a1 += bfhi(u1);
    }
    for (; e + 8 <= hi; e += 8) {
        int s = ssrc[e + eo];
        unsigned u = h2s[(size_t)s * 8 + g];
        a0 += bflo(u); a1 += bfhi(u);
    }
    if (eo < hi - e) {
        int s = ssrc[e + eo];
        unsigned u = h2s[(size_t)s * 8 + g];
        a0 += bflo(u); a1 += bfhi(u);
    }

    a0 += __shfl_xor(a0, 8);  a1 += __shfl_xor(a1, 8);
    a0 += __shfl_xor(a0, 16); a1 += __shfl_xor(a1, 16);
    a0 += __shfl_xor(a0, 32); a1 += __shfl_xor(a1, 32);

    float dd = dinv[node];
    float2 bb = *(const float2*)(b2 + 2 * g);
    float v0 = fmaf(dd, a0, bb.x);
    float v1 = fmaf(dd, a1, bb.y);

    float m = fmaxf(v0, v1);
#pragma unroll
    for (int msk = 1; msk < 8; msk <<= 1) m = fmaxf(m, __shfl_xor(m, msk));
    float s2 = __expf(v0 - m) + __expf(v1 - m);
#pragma unroll
    for (int msk = 1; msk < 8; msk <<= 1) s2 += __shfl_xor(s2, msk);
    float lse = m + __logf(s2);
    if (eo == 0) {
        float2 o; o.x = v0 - lse; o.y = v1 - lse;
        *(float2*)(out + (size_t)node * OUT_DIM + 2 * g) = o;
    }
}

extern "C" void kernel_launch(void* const* d_in, const int* in_sizes, int n_in,
                              void* d_out, int out_size, void* d_ws, size_t ws_size,
                              hipStream_t stream) {
    const float* x  = (const float*)d_in[0];
    const int*   ei = (const int*)d_in[1];
    const float* W1 = (const float*)d_in[2];
    const float* b1 = (const float*)d_in[3];
    const float* W2 = (const float*)d_in[4];
    const float* b2 = (const float*)d_in[5];
    float* out = (float*)d_out;

    const int n = N_NODES;
    const int e = E_EDGES;
    const int* srcp = ei;        // edge_index[0]
    const int* dstp = ei + e;    // edge_index[1]

    // workspace layout
    char* w = (char*)d_ws;
    int*      cnt_bb = (int*)w;        w += (size_t)NBUCK * NBLK * 4;
    int*      btot   = (int*)w;        w += (size_t)NBUCK * 4;
    int*      bbase  = (int*)w;        w += (size_t)(NBUCK + 1) * 4;
    int*      rowptr = (int*)w;        w += (size_t)(n + 1) * 4;
    float*    dinv   = (float*)w;      w += (size_t)n * 4;
    unsigned* tmp    = (unsigned*)w;   w += (size_t)e * 4;
    int*      ssrc   = (int*)w;        w += (size_t)e * 4;
    short*    h1s    = (short*)w;      w += (size_t)n * HID * 2;     // bf16, UNSCALED
    short*    h2s    = (short*)w;      w += (size_t)n * OUT_DIM * 2; // bf16

    auto blk = [](long long total, int b) { return (int)((total + b - 1) / b); };

    // K1: layer-1 GEMM (independent of CSR now) runs concurrently with csr_a
    k1_gemm1_csra<<<GB1 + NBLK, 512, 0, stream>>>(x, W1, (const int4*)dstp, cnt_bb, h1s);
    // K2: per-bucket scan over blocks
    csr_b1<<<NBUCK, NBLK, 0, stream>>>(cnt_bb, btot);
    // K3: bucket scatter (inline bbase scan; block 0 publishes bbase)
    csr_c2<<<NBLK, 512, 0, stream>>>((const int4*)srcp, (const int4*)dstp,
                                     cnt_bb, btot, bbase, tmp);
    // K4: within-bucket sort -> rowptr/dinv/ssrc
    csr_p2<<<NBUCK, 256, 0, stream>>>(tmp, bbase, rowptr, dinv, ssrc);
    // K5: fused aggregate + bias/ReLU + W2 transform + dinv scale
    agg1_gemm2<<<3200, 256, 0, stream>>>(h1s, dinv, b1, W2, rowptr, ssrc, h2s);
    // K6: layer-2 aggregate + bias + log_softmax
    agg2_pull<<<blk(n, 4), 256, 0, stream>>>((const unsigned*)h2s, dinv, b2,
                                             rowptr, ssrc, out);
}

// Round 2
// 189.561 us; speedup vs baseline: 1.0551x; 1.0551x over previous
//
#include <hip/hip_runtime.h>
#include <hip/hip_bf16.h>

#define N_NODES 50000
#define E_EDGES 800000
#define IN_DIM  256
#define HID     128
#define OUT_DIM 16

#define NBUCK 391    // ceil(50000/128) buckets of 128 nodes (dst>>7)
#define NBLK  128    // blocks for bucket phases A/C
#define P2CAP 4096   // max edges per bucket (mean 2046, sigma ~45)
#define GB1   391    // gemm1 blocks: ceil(50000/128)

using frag_ab = __attribute__((ext_vector_type(8))) short;  // 8 bf16
using frag_cd = __attribute__((ext_vector_type(4))) float;  // 4 fp32

static __device__ inline short f2bf(float f) {
    union { float f; unsigned u; } v; v.f = f;
    unsigned r = (v.u + 0x7fffu + ((v.u >> 16) & 1u)) >> 16;
    return (short)r;
}
static __device__ inline float bflo(unsigned u) {
    union { unsigned u; float f; } v; v.u = u << 16; return v.f;
}
static __device__ inline float bfhi(unsigned u) {
    union { unsigned u; float f; } v; v.u = u & 0xffff0000u; return v.f;
}
static __device__ inline unsigned packbf(float a, float b) {
    return (unsigned)(unsigned short)f2bf(a) | ((unsigned)(unsigned short)f2bf(b) << 16);
}

// ===== K1: gemm1 (inline W1 transform, UNSCALED h1s) || csr_a || w2t ========
// blocks [0, GB1): layer-1 dense transform, h1s = bf16(x @ W1)  (no dinv)
// blocks [GB1, GB1+NBLK): dst histogram into per-block bucket counts
// block  [GB1+NBLK]: W2 -> column-major bf16 (w2t[n][k])
__global__ __launch_bounds__(512) void k1_gemm1_csra(const float* __restrict__ x,
                                                     const float* __restrict__ W1,
                                                     const int4* __restrict__ dst4,
                                                     const float* __restrict__ W2,
                                                     int* __restrict__ cnt_bb,
                                                     short* __restrict__ w2t,
                                                     short* __restrict__ h1s) {
    __shared__ uint4 lwt[64 * 64];   // 64 KB (aliased as int hist[] for csr_a blocks)
    int tid = threadIdx.x;

    if (blockIdx.x == GB1 + NBLK) {
        // ---- w2t: W2 [128x16] f32 -> col-major bf16 [16][128]
        int n0 = tid >> 5, k0 = (tid & 31) * 4;
#pragma unroll
        for (int i = 0; i < 4; ++i)
            w2t[n0 * HID + k0 + i] = f2bf(W2[(k0 + i) * OUT_DIM + n0]);
        return;
    }
    if (blockIdx.x >= GB1) {
        // ---- csr_a: bucket histogram (512-thread partition; csr_c2 must match!)
        int* hist = (int*)lwt;
        int bb = blockIdx.x - GB1;
        for (int i = tid; i < NBUCK; i += 512) hist[i] = 0;
        __syncthreads();
        for (int i = bb * 512 + tid; i < E_EDGES / 4; i += NBLK * 512) {
            int4 d = dst4[i];
            atomicAdd(&hist[d.x >> 7], 1);
            atomicAdd(&hist[d.y >> 7], 1);
            atomicAdd(&hist[d.z >> 7], 1);
            atomicAdd(&hist[d.w >> 7], 1);
        }
        __syncthreads();
        for (int i = tid; i < NBUCK; i += 512) cnt_bb[i * NBLK + bb] = hist[i];
        return;
    }

    // ---- gemm1: build fragment-major bf16 W1 tile in LDS directly from f32 W1
#pragma unroll
    for (int it = 0; it < 8; ++it) {
        int j = it * 512 + tid;
        int f = j >> 6, lane_ = j & 63;
        int kt = f >> 3, tt = f & 7;
        int mm = lane_ & 15, qq = lane_ >> 4;
        int c = tt * 16 + mm;
        int k0 = kt * 32 + qq * 8;
        unsigned p[4];
#pragma unroll
        for (int i = 0; i < 4; ++i)
            p[i] = packbf(W1[(k0 + 2 * i) * HID + c], W1[(k0 + 2 * i + 1) * HID + c]);
        uint4 v; v.x = p[0]; v.y = p[1]; v.z = p[2]; v.w = p[3];
        lwt[j] = v;
    }

    int wave = tid >> 6;
    int lane = tid & 63;
    int m = lane & 15;
    int q = lane >> 4;
    int row0 = blockIdx.x * 128 + wave * 16;
    int arow_idx = row0 + m;
    const float4* arow4 = (const float4*)(x + (size_t)(arow_idx < N_NODES ? arow_idx : 0) * IN_DIM);

    frag_ab a[8];
#pragma unroll
    for (int kt = 0; kt < 8; ++kt) {
        float4 f0 = arow4[kt * 8 + q * 2];
        float4 f1 = arow4[kt * 8 + q * 2 + 1];
        a[kt][0] = f2bf(f0.x); a[kt][1] = f2bf(f0.y); a[kt][2] = f2bf(f0.z); a[kt][3] = f2bf(f0.w);
        a[kt][4] = f2bf(f1.x); a[kt][5] = f2bf(f1.y); a[kt][6] = f2bf(f1.z); a[kt][7] = f2bf(f1.w);
    }

    frag_cd acc[8];
#pragma unroll
    for (int t = 0; t < 8; ++t) acc[t] = frag_cd{0.f, 0.f, 0.f, 0.f};

    __syncthreads();

#pragma unroll
    for (int kt = 0; kt < 8; ++kt) {
#pragma unroll
        for (int t = 0; t < 8; ++t) {
            frag_ab b = *(const frag_ab*)&lwt[(kt * 8 + t) * 64 + lane];
            acc[t] = __builtin_amdgcn_mfma_f32_16x16x32_bf16(a[kt], b, acc[t], 0, 0, 0);
        }
    }

#pragma unroll
    for (int t = 0; t < 8; ++t) {
#pragma unroll
        for (int r = 0; r < 4; ++r) {
            int orow = row0 + q * 4 + r;
            if (orow < N_NODES)
                h1s[(size_t)orow * HID + t * 16 + m] = f2bf(acc[t][r]);   // unscaled
        }
    }
}

// ========== K2: per-bucket exclusive scan over blocks (unchanged) ===========
__global__ __launch_bounds__(NBLK) void csr_b1(int* __restrict__ cnt_bb,
                                               int* __restrict__ btot) {
    __shared__ int sm[NBLK];
    int b = blockIdx.x, t = threadIdx.x;
    int v = cnt_bb[b * NBLK + t];
    sm[t] = v;
    __syncthreads();
    for (int o = 1; o < NBLK; o <<= 1) {
        int u = (t >= o) ? sm[t - o] : 0;
        __syncthreads();
        sm[t] += u;
        __syncthreads();
    }
    cnt_bb[b * NBLK + t] = sm[t] - v;
    if (t == NBLK - 1) btot[b] = sm[t];
}

// ========== K3: csr_c with inline bucket-base scan ===========================
__global__ __launch_bounds__(512) void csr_c2(const int4* __restrict__ src4,
                                              const int4* __restrict__ dst4,
                                              const int* __restrict__ cnt_bb,
                                              const int* __restrict__ btot,
                                              int* __restrict__ bbase,
                                              unsigned* __restrict__ tmp) {
    __shared__ int run[NBUCK];
    __shared__ int sc[512];
    int t = threadIdx.x;
    int v = (t < NBUCK) ? btot[t] : 0;
    sc[t] = v;
    __syncthreads();
    for (int o = 1; o < 512; o <<= 1) {
        int u = (t >= o) ? sc[t - o] : 0;
        __syncthreads();
        sc[t] += u;
        __syncthreads();
    }
    if (t < NBUCK) {
        int exc = sc[t] - v;
        run[t] = exc + cnt_bb[t * NBLK + blockIdx.x];
        if (blockIdx.x == 0) bbase[t] = exc;
    }
    if (blockIdx.x == 0 && t == 511) bbase[NBUCK] = sc[511];
    __syncthreads();
    for (int i = blockIdx.x * 512 + t; i < E_EDGES / 4; i += NBLK * 512) {
        int4 d = dst4[i];
        int4 s = src4[i];
        int p0 = atomicAdd(&run[d.x >> 7], 1);
        tmp[p0] = (unsigned)s.x | ((unsigned)(d.x & 127) << 17);
        int p1 = atomicAdd(&run[d.y >> 7], 1);
        tmp[p1] = (unsigned)s.y | ((unsigned)(d.y & 127) << 17);
        int p2 = atomicAdd(&run[d.z >> 7], 1);
        tmp[p2] = (unsigned)s.z | ((unsigned)(d.z & 127) << 17);
        int p3 = atomicAdd(&run[d.w >> 7], 1);
        tmp[p3] = (unsigned)s.w | ((unsigned)(d.w & 127) << 17);
    }
}

// ===== K4: within-bucket counting sort -> rowptr/dinv/ssrc + scale h1s ======
// NEW: after computing dinv for its 128 nodes, this block scales the h1s rows
// in place (h1s written by K1, complete by now). Coalesced 32KB R+W per block.
__global__ __launch_bounds__(256) void csr_p2s(const unsigned* __restrict__ tmp,
                                               const int* __restrict__ bbase,
                                               int* __restrict__ rowptr,
                                               float* __restrict__ dinv,
                                               int* __restrict__ ssrc,
                                               short* __restrict__ h1s) {
    __shared__ unsigned ed[P2CAP];
    __shared__ int cnt[128];
    __shared__ int off[128];
    __shared__ float sdv[128];
    int b = blockIdx.x, t = threadIdx.x;
    int base = bbase[b];
    int m = bbase[b + 1] - base;
    if (m > P2CAP) m = P2CAP;
    if (t < 128) cnt[t] = 0;
    __syncthreads();
    for (int i = t; i < m; i += 256) {
        unsigned v = tmp[base + i];
        ed[i] = v;
        atomicAdd(&cnt[v >> 17], 1);
    }
    __syncthreads();
    if (t < 128) off[t] = cnt[t];
    __syncthreads();
    for (int o = 1; o < 128; o <<= 1) {
        int u = (t >= o && t < 128) ? off[t - o] : 0;
        __syncthreads();
        if (t < 128) off[t] += u;
        __syncthreads();
    }
    if (t < 128) {
        int node = b * 128 + t;
        int ex = off[t] - cnt[t];
        float dv = rsqrtf((float)(cnt[t] + 1));
        sdv[t] = dv;
        if (node < N_NODES) {
            rowptr[node] = base + ex;
            dinv[node] = dv;
        }
        off[t] = ex;
    }
    if (b == NBUCK - 1 && t == 0) rowptr[N_NODES] = E_EDGES;
    __syncthreads();
    for (int i = t; i < m; i += 256) {
        unsigned v = ed[i];
        int p = atomicAdd(&off[v >> 17], 1);
        ssrc[base + p] = (int)(v & 0x1FFFF);
    }
    // scale h1s rows for this bucket's nodes: row *= dinv[node]
    for (int idx = t; idx < 128 * 16; idx += 256) {
        int nl = idx >> 4;           // node within bucket
        int wd = idx & 15;           // uint4 word within row (16 x 16B = 256B)
        int node = b * 128 + nl;
        if (node < N_NODES) {
            uint4* p = (uint4*)(h1s + (size_t)node * HID) + wd;
            uint4 u = *p;
            float dv = sdv[nl];
            u.x = packbf(dv * bflo(u.x), dv * bfhi(u.x));
            u.y = packbf(dv * bflo(u.y), dv * bfhi(u.y));
            u.z = packbf(dv * bflo(u.z), dv * bfhi(u.z));
            u.w = packbf(dv * bflo(u.w), dv * bfhi(u.w));
            *p = u;
        }
    }
}

// ===== K5: layer-1 pull: gather + reduce + bias/ReLU -> bf16 out1 ===========
__global__ __launch_bounds__(256) void agg1_pull(const short* __restrict__ h1s,
                                                 const float* __restrict__ dinv,
                                                 const float* __restrict__ b1,
                                                 const int* __restrict__ rowptr,
                                                 const int* __restrict__ ssrc,
                                                 uint4* __restrict__ out1) {
    int wave = threadIdx.x >> 6;
    int lane = threadIdx.x & 63;
    int node = __builtin_amdgcn_readfirstlane(blockIdx.x * 4 + wave);
    if (node >= N_NODES) return;
    int eo = lane >> 4;       // edge slot in quad
    int g  = lane & 15;       // feature octet

    int lo = rowptr[node], hi = rowptr[node + 1];
    float dd = dinv[node];
    float a0 = 0.f, a1 = 0.f, a2 = 0.f, a3 = 0.f;
    float a4 = 0.f, a5 = 0.f, a6 = 0.f, a7 = 0.f;

    if (eo == 0) {   // self-loop row
        uint4 u = *(const uint4*)(h1s + (size_t)node * HID + g * 8);
        a0 = bflo(u.x); a1 = bfhi(u.x); a2 = bflo(u.y); a3 = bfhi(u.y);
        a4 = bflo(u.z); a5 = bfhi(u.z); a6 = bflo(u.w); a7 = bfhi(u.w);
    }

    int e = lo;
    for (; e + 16 <= hi; e += 16) {
        int s0 = ssrc[e + eo];
        int s1 = ssrc[e + 4 + eo];
        int s2 = ssrc[e + 8 + eo];
        int s3 = ssrc[e + 12 + eo];
        uint4 u0 = *(const uint4*)(h1s + (size_t)s0 * HID + g * 8);
        uint4 u1 = *(const uint4*)(h1s + (size_t)s1 * HID + g * 8);
        uint4 u2 = *(const uint4*)(h1s + (size_t)s2 * HID + g * 8);
        uint4 u3 = *(const uint4*)(h1s + (size_t)s3 * HID + g * 8);
        a0 += bflo(u0.x); a1 += bfhi(u0.x); a2 += bflo(u0.y); a3 += bfhi(u0.y);
        a4 += bflo(u0.z); a5 += bfhi(u0.z); a6 += bflo(u0.w); a7 += bfhi(u0.w);
        a0 += bflo(u1.x); a1 += bfhi(u1.x); a2 += bflo(u1.y); a3 += bfhi(u1.y);
        a4 += bflo(u1.z); a5 += bfhi(u1.z); a6 += bflo(u1.w); a7 += bfhi(u1.w);
        a0 += bflo(u2.x); a1 += bfhi(u2.x); a2 += bflo(u2.y); a3 += bfhi(u2.y);
        a4 += bflo(u2.z); a5 += bfhi(u2.z); a6 += bflo(u2.w); a7 += bfhi(u2.w);
        a0 += bflo(u3.x); a1 += bfhi(u3.x); a2 += bflo(u3.y); a3 += bfhi(u3.y);
        a4 += bflo(u3.z); a5 += bfhi(u3.z); a6 += bflo(u3.w); a7 += bfhi(u3.w);
    }
    for (; e + 4 <= hi; e += 4) {
        int s = ssrc[e + eo];
        uint4 u = *(const uint4*)(h1s + (size_t)s * HID + g * 8);
        a0 += bflo(u.x); a1 += bfhi(u.x); a2 += bflo(u.y); a3 += bfhi(u.y);
        a4 += bflo(u.z); a5 += bfhi(u.z); a6 += bflo(u.w); a7 += bfhi(u.w);
    }
    if (eo < hi - e) {
        int s = ssrc[e + eo];
        uint4 u = *(const uint4*)(h1s + (size_t)s * HID + g * 8);
        a0 += bflo(u.x); a1 += bfhi(u.x); a2 += bflo(u.y); a3 += bfhi(u.y);
        a4 += bflo(u.z); a5 += bfhi(u.z); a6 += bflo(u.w); a7 += bfhi(u.w);
    }

    a0 += __shfl_xor(a0, 16); a1 += __shfl_xor(a1, 16);
    a2 += __shfl_xor(a2, 16); a3 += __shfl_xor(a3, 16);
    a4 += __shfl_xor(a4, 16); a5 += __shfl_xor(a5, 16);
    a6 += __shfl_xor(a6, 16); a7 += __shfl_xor(a7, 16);
    a0 += __shfl_xor(a0, 32); a1 += __shfl_xor(a1, 32);
    a2 += __shfl_xor(a2, 32); a3 += __shfl_xor(a3, 32);
    a4 += __shfl_xor(a4, 32); a5 += __shfl_xor(a5, 32);
    a6 += __shfl_xor(a6, 32); a7 += __shfl_xor(a7, 32);

    if (eo == 0) {
        float4 bA = *(const float4*)(b1 + g * 8);
        float4 bB = *(const float4*)(b1 + g * 8 + 4);
        float o0 = fmaxf(fmaf(dd, a0, bA.x), 0.f);
        float o1 = fmaxf(fmaf(dd, a1, bA.y), 0.f);
        float o2 = fmaxf(fmaf(dd, a2, bA.z), 0.f);
        float o3 = fmaxf(fmaf(dd, a3, bA.w), 0.f);
        float o4 = fmaxf(fmaf(dd, a4, bB.x), 0.f);
        float o5 = fmaxf(fmaf(dd, a5, bB.y), 0.f);
        float o6 = fmaxf(fmaf(dd, a6, bB.z), 0.f);
        float o7 = fmaxf(fmaf(dd, a7, bB.w), 0.f);
        uint4 st;
        st.x = packbf(o0, o1); st.y = packbf(o2, o3);
        st.z = packbf(o4, o5); st.w = packbf(o6, o7);
        out1[(size_t)node * 16 + g] = st;
    }
}

// ===== K6: layer-2 transform via MFMA: h2s = (out1 @ W2) * dinv, bf16 out ===
__global__ __launch_bounds__(256) void gemm2_mfma(const short* __restrict__ out1,
                                                  const short* __restrict__ w2t,
                                                  const float* __restrict__ dinv,
                                                  short* __restrict__ h2s) {
    int wave = threadIdx.x >> 6;
    int lane = threadIdx.x & 63;
    int m = lane & 15;
    int q = lane >> 4;
    int row0 = blockIdx.x * 64 + wave * 16;
    int arow = row0 + m;
    if (arow >= N_NODES) arow = N_NODES - 1;   // clamp loads
    const short* ap = out1 + (size_t)arow * HID + q * 8;
    const short* bp = w2t + m * HID + q * 8;

    frag_cd acc = frag_cd{0.f, 0.f, 0.f, 0.f};
#pragma unroll
    for (int kt = 0; kt < 4; ++kt) {
        frag_ab a = *(const frag_ab*)(ap + kt * 32);
        frag_ab b = *(const frag_ab*)(bp + kt * 32);
        acc = __builtin_amdgcn_mfma_f32_16x16x32_bf16(a, b, acc, 0, 0, 0);
    }
#pragma unroll
    for (int r = 0; r < 4; ++r) {
        int row = row0 + q * 4 + r;
        if (row < N_NODES)
            h2s[(size_t)row * OUT_DIM + m] = f2bf(acc[r] * dinv[row]);
    }
}

// ===== K7: layer-2 pull (bf16 rows, 16 edges/iter) + bias + log_softmax =====
__global__ __launch_bounds__(256) void agg2_pull(const unsigned* __restrict__ h2s,
                                                 const float* __restrict__ dinv,
                                                 const float* __restrict__ b2,
                                                 const int* __restrict__ rowptr,
                                                 const int* __restrict__ ssrc,
                                                 float* __restrict__ out) {
    int wave = threadIdx.x >> 6;
    int lane = threadIdx.x & 63;
    int node = __builtin_amdgcn_readfirstlane(blockIdx.x * 4 + wave);
    if (node >= N_NODES) return;
    int eo = lane >> 3;
    int g  = lane & 7;

    int lo = rowptr[node], hi = rowptr[node + 1];
    float a0 = 0.f, a1 = 0.f;
    if (eo == 0) {
        unsigned u = h2s[(size_t)node * 8 + g];
        a0 = bflo(u); a1 = bfhi(u);
    }
    int e = lo;
    for (; e + 16 <= hi; e += 16) {
        int s0 = ssrc[e + eo];
        int s1 = ssrc[e + 8 + eo];
        unsigned u0 = h2s[(size_t)s0 * 8 + g];
        unsigned u1 = h2s[(size_t)s1 * 8 + g];
        a0 += bflo(u0); a1 += bfhi(u0);
        a0 += bflo(u1); a1 += bfhi(u1);
    }
    for (; e + 8 <= hi; e += 8) {
        int s = ssrc[e + eo];
        unsigned u = h2s[(size_t)s * 8 + g];
        a0 += bflo(u); a1 += bfhi(u);
    }
    if (eo < hi - e) {
        int s = ssrc[e + eo];
        unsigned u = h2s[(size_t)s * 8 + g];
        a0 += bflo(u); a1 += bfhi(u);
    }

    a0 += __shfl_xor(a0, 8);  a1 += __shfl_xor(a1, 8);
    a0 += __shfl_xor(a0, 16); a1 += __shfl_xor(a1, 16);
    a0 += __shfl_xor(a0, 32); a1 += __shfl_xor(a1, 32);

    float dd = dinv[node];
    float2 bb = *(const float2*)(b2 + 2 * g);
    float v0 = fmaf(dd, a0, bb.x);
    float v1 = fmaf(dd, a1, bb.y);

    float m = fmaxf(v0, v1);
#pragma unroll
    for (int msk = 1; msk < 8; msk <<= 1) m = fmaxf(m, __shfl_xor(m, msk));
    float s2 = __expf(v0 - m) + __expf(v1 - m);
#pragma unroll
    for (int msk = 1; msk < 8; msk <<= 1) s2 += __shfl_xor(s2, msk);
    float lse = m + __logf(s2);
    if (eo == 0) {
        float2 o; o.x = v0 - lse; o.y = v1 - lse;
        *(float2*)(out + (size_t)node * OUT_DIM + 2 * g) = o;
    }
}

extern "C" void kernel_launch(void* const* d_in, const int* in_sizes, int n_in,
                              void* d_out, int out_size, void* d_ws, size_t ws_size,
                              hipStream_t stream) {
    const float* x  = (const float*)d_in[0];
    const int*   ei = (const int*)d_in[1];
    const float* W1 = (const float*)d_in[2];
    const float* b1 = (const float*)d_in[3];
    const float* W2 = (const float*)d_in[4];
    const float* b2 = (const float*)d_in[5];
    float* out = (float*)d_out;

    const int n = N_NODES;
    const int e = E_EDGES;
    const int* srcp = ei;        // edge_index[0]
    const int* dstp = ei + e;    // edge_index[1]

    // workspace layout
    char* w = (char*)d_ws;
    int*      cnt_bb = (int*)w;        w += (size_t)NBUCK * NBLK * 4;
    int*      btot   = (int*)w;        w += (size_t)NBUCK * 4;
    int*      bbase  = (int*)w;        w += (size_t)(NBUCK + 1) * 4;
    int*      rowptr = (int*)w;        w += (size_t)(n + 1) * 4;
    float*    dinv   = (float*)w;      w += (size_t)n * 4;
    unsigned* tmp    = (unsigned*)w;   w += (size_t)e * 4;
    int*      ssrc   = (int*)w;        w += (size_t)e * 4;
    short*    w2t    = (short*)w;      w += (size_t)OUT_DIM * HID * 2;  // col-major bf16 W2
    short*    h1s    = (short*)w;      w += (size_t)n * HID * 2;     // bf16; scaled by csr_p2s
    short*    out1   = (short*)w;      w += (size_t)n * HID * 2;     // bf16 relu'd layer-1 out
    short*    h2s    = (short*)w;      w += (size_t)n * OUT_DIM * 2; // bf16

    auto blk = [](long long total, int b) { return (int)((total + b - 1) / b); };

    // K1: layer-1 GEMM (unscaled; independent of CSR) || csr_a || w2t
    k1_gemm1_csra<<<GB1 + NBLK + 1, 512, 0, stream>>>(x, W1, (const int4*)dstp, W2,
                                                      cnt_bb, w2t, h1s);
    // K2: per-bucket scan over blocks
    csr_b1<<<NBUCK, NBLK, 0, stream>>>(cnt_bb, btot);
    // K3: bucket scatter (inline bbase scan; block 0 publishes bbase)
    csr_c2<<<NBLK, 512, 0, stream>>>((const int4*)srcp, (const int4*)dstp,
                                     cnt_bb, btot, bbase, tmp);
    // K4: within-bucket sort -> rowptr/dinv/ssrc; scales h1s rows in place
    csr_p2s<<<NBUCK, 256, 0, stream>>>(tmp, bbase, rowptr, dinv, ssrc, h1s);
    // K5: layer-1 aggregate + bias/ReLU -> out1 (bf16)
    agg1_pull<<<blk(n, 4), 256, 0, stream>>>(h1s, dinv, b1, rowptr, ssrc, (uint4*)out1);
    // K6: layer-2 dense transform (MFMA), pre-scaled by dinv
    gemm2_mfma<<<blk(n, 64), 256, 0, stream>>>(out1, w2t, dinv, h2s);
    // K7: layer-2 aggregate + bias + log_softmax
    agg2_pull<<<blk(n, 4), 256, 0, stream>>>((const unsigned*)h2s, dinv, b2,
                                             rowptr, ssrc, out);
}